// Round 2
// baseline (2811.362 us; speedup 1.0000x reference)
//
#include <hip/hip_runtime.h>

#define N_NODES 50000
#define N_EDGES 1600000
#define R_REL   20
#define BN_EPS  1e-5f
#define SEGS    (N_NODES * R_REL)        /* 1,000,000 */
#define SCAN_NB ((SEGS + 1023) / 1024)   /* 977 */

// ---------------- CSR build: count per (dst,rel) segment ----------------
__global__ void count_kernel(const int* __restrict__ dst, const int* __restrict__ et,
                             int* __restrict__ cnt) {
    int stride = gridDim.x * blockDim.x;
    for (int e = blockIdx.x * blockDim.x + threadIdx.x; e < N_EDGES; e += stride)
        atomicAdd(&cnt[dst[e] * R_REL + et[e]], 1);
}

// ---------------- 2-level exclusive scan over SEGS entries ----------------
// level 1: each block scans 1024 elements (256 thr x 4), writes block sums
__global__ __launch_bounds__(256) void scan1_kernel(const int* __restrict__ in,
                                                    int* __restrict__ out,
                                                    int* __restrict__ bsums, int n) {
    __shared__ int lds[256];
    int tid  = threadIdx.x;
    int base = blockIdx.x * 1024 + tid * 4;
    int v[4];
    #pragma unroll
    for (int j = 0; j < 4; ++j) v[j] = (base + j < n) ? in[base + j] : 0;
    int tsum = v[0] + v[1] + v[2] + v[3];
    lds[tid] = tsum;
    __syncthreads();
    for (int off = 1; off < 256; off <<= 1) {
        int t = (tid >= off) ? lds[tid - off] : 0;
        __syncthreads();
        lds[tid] += t;
        __syncthreads();
    }
    int excl = lds[tid] - tsum;
    int run = excl;
    #pragma unroll
    for (int j = 0; j < 4; ++j) {
        if (base + j < n) out[base + j] = run;
        run += v[j];
    }
    if (tid == 255) bsums[blockIdx.x] = lds[255];
}

// level 2: single block scans the (<=1024) block sums, in-place exclusive
__global__ __launch_bounds__(1024) void scan_top_kernel(int* __restrict__ bsums, int nb) {
    __shared__ int lds[1024];
    int tid = threadIdx.x;
    int v = (tid < nb) ? bsums[tid] : 0;
    lds[tid] = v;
    __syncthreads();
    for (int off = 1; off < 1024; off <<= 1) {
        int t = (tid >= off) ? lds[tid - off] : 0;
        __syncthreads();
        lds[tid] += t;
        __syncthreads();
    }
    bsums[tid] = lds[tid] - v;
}

// level 3: add block offsets
__global__ void scan_add_kernel(int* __restrict__ out, const int* __restrict__ bsums, int n) {
    int stride = gridDim.x * blockDim.x;
    for (int i = blockIdx.x * blockDim.x + threadIdx.x; i < n; i += stride)
        out[i] += bsums[i >> 10];
}

__global__ void set_total_kernel(int* __restrict__ offs) {
    offs[SEGS] = N_EDGES;
}

// ---------------- bucket-fill: esrc grouped by segment ----------------
__global__ void fill_kernel(const int* __restrict__ src, const int* __restrict__ dst,
                            const int* __restrict__ et, const int* __restrict__ offs,
                            int* __restrict__ fill, int* __restrict__ esrc) {
    int stride = gridDim.x * blockDim.x;
    for (int e = blockIdx.x * blockDim.x + threadIdx.x; e < N_EDGES; e += stride) {
        int seg = dst[e] * R_REL + et[e];
        int pos = offs[seg] + atomicAdd(&fill[seg], 1);
        esrc[pos] = src[e];
    }
}

// ---------------- fused layer: gather-mean + per-rel GEMM + root + bias + BN (+ReLU) ----
// 64-node tile / block, 256 threads (4 waves). Loop r=0..R: gather agg[64][F] into LDS,
// stage W[r][F][64] into LDS, accumulate. r==R is the root term (A = hin tile, W = root).
// GEMM mapping: thread = (og = tid&15 -> 4 outputs, nl = tid>>4 -> nodes nl+{0,16,32,48}).
template <int F, bool RELU>
__global__ __launch_bounds__(256) void rgcn_layer(
    const float* __restrict__ hin, const int* __restrict__ offs,
    const int* __restrict__ esrc,
    const float* __restrict__ W, const float* __restrict__ root,
    const float* __restrict__ bias, const float* __restrict__ gamma,
    const float* __restrict__ beta, const float* __restrict__ rmean,
    const float* __restrict__ rvar, float* __restrict__ out) {
    constexpr int TN = 64;
    constexpr int AP = F + 4;   // padded LDS row stride
    constexpr int FV = F / 4;

    __shared__ float Alds[TN * AP];
    __shared__ float Wlds[F * 64];

    const int tid  = threadIdx.x;
    const int lane = tid & 63;
    const int wv   = tid >> 6;
    const int og   = tid & 15;
    const int nl   = tid >> 4;
    const int o    = og * 4;
    const int n0   = blockIdx.x * TN;

    float acc[4][4];
    #pragma unroll
    for (int k = 0; k < 4; ++k)
        #pragma unroll
        for (int q = 0; q < 4; ++q) acc[k][q] = 0.f;

    for (int r = 0; r <= R_REL; ++r) {
        __syncthreads();   // previous iteration's readers done before overwrite
        if (r < R_REL) {
            if (F == 64) {
                // wave wv handles nodes wv*16..wv*16+15; lane = feature
                #pragma unroll 1
                for (int k = 0; k < 16; ++k) {
                    int n  = wv * 16 + k;
                    int gn = n0 + n;
                    float s = 0.f;
                    if (gn < N_NODES) {
                        int seg = gn * R_REL + r;
                        int e0 = offs[seg], e1 = offs[seg + 1];
                        for (int e = e0; e < e1; ++e)
                            s += hin[(size_t)esrc[e] * 64 + lane];
                        int c = e1 - e0;
                        s *= 1.0f / (float)(c > 0 ? c : 1);
                    }
                    Alds[n * AP + lane] = s;
                }
            } else {
                // F==4: lane>>2 = node-within-16, lane&3 = feature
                int n  = wv * 16 + (lane >> 2);
                int f  = lane & 3;
                int gn = n0 + n;
                float s = 0.f;
                if (gn < N_NODES) {
                    int seg = gn * R_REL + r;
                    int e0 = offs[seg], e1 = offs[seg + 1];
                    for (int e = e0; e < e1; ++e)
                        s += hin[(size_t)esrc[e] * 4 + f];
                    int c = e1 - e0;
                    s *= 1.0f / (float)(c > 0 ? c : 1);
                }
                Alds[n * AP + f] = s;
            }
            const float* Wb = W + (size_t)r * F * 64;
            for (int v = tid; v < F * 16; v += 256)
                *(float4*)&Wlds[v * 4] = *(const float4*)&Wb[v * 4];
        } else {
            // root term: A = hin tile rows
            for (int v = tid; v < TN * FV; v += 256) {
                int n = v / FV, c = v % FV;
                int gn = n0 + n;
                float4 val = make_float4(0.f, 0.f, 0.f, 0.f);
                if (gn < N_NODES)
                    val = *(const float4*)&hin[(size_t)gn * F + c * 4];
                *(float4*)&Alds[n * AP + c * 4] = val;
            }
            for (int v = tid; v < F * 16; v += 256)
                *(float4*)&Wlds[v * 4] = *(const float4*)&root[v * 4];
        }
        __syncthreads();

        #pragma unroll
        for (int c = 0; c < FV; ++c) {
            float a[4][4];
            #pragma unroll
            for (int k = 0; k < 4; ++k)
                *(float4*)a[k] = *(const float4*)&Alds[(nl + k * 16) * AP + c * 4];
            #pragma unroll
            for (int j = 0; j < 4; ++j) {
                float w[4];
                *(float4*)w = *(const float4*)&Wlds[(c * 4 + j) * 64 + o];
                #pragma unroll
                for (int k = 0; k < 4; ++k)
                    #pragma unroll
                    for (int q = 0; q < 4; ++q)
                        acc[k][q] += a[k][j] * w[q];
            }
        }
    }

    // epilogue: bias + BN (+ReLU)
    float bia[4], rm[4], rv[4], g[4], bt[4], sc[4];
    *(float4*)bia = *(const float4*)&bias[o];
    *(float4*)rm  = *(const float4*)&rmean[o];
    *(float4*)rv  = *(const float4*)&rvar[o];
    *(float4*)g   = *(const float4*)&gamma[o];
    *(float4*)bt  = *(const float4*)&beta[o];
    #pragma unroll
    for (int q = 0; q < 4; ++q) sc[q] = g[q] * rsqrtf(rv[q] + BN_EPS);

    #pragma unroll
    for (int k = 0; k < 4; ++k) {
        int gn = n0 + nl + k * 16;
        if (gn < N_NODES) {
            float ov[4];
            #pragma unroll
            for (int q = 0; q < 4; ++q) {
                float v = acc[k][q] + bia[q];
                v = (v - rm[q]) * sc[q] + bt[q];
                if (RELU) v = fmaxf(v, 0.f);
                ov[q] = v;
            }
            *(float4*)&out[(size_t)gn * 64 + o] = *(const float4*)ov;
        }
    }
}

extern "C" void kernel_launch(void* const* d_in, const int* in_sizes, int n_in,
                              void* d_out, int out_size, void* d_ws, size_t ws_size,
                              hipStream_t stream) {
    const float* x     = (const float*)d_in[0];
    const int*   ei    = (const int*)d_in[1];
    const int*   et    = (const int*)d_in[2];
    const float* W0    = (const float*)d_in[3];
    const float* root0 = (const float*)d_in[4];
    const float* b0    = (const float*)d_in[5];
    const float* Wh    = (const float*)d_in[6];
    const float* rooth = (const float*)d_in[7];
    const float* bh    = (const float*)d_in[8];
    const float* gamma = (const float*)d_in[9];
    const float* beta  = (const float*)d_in[10];
    const float* rmean = (const float*)d_in[11];
    const float* rvar  = (const float*)d_in[12];
    float* out = (float*)d_out;

    const int* src = ei;
    const int* dst = ei + N_EDGES;

    // workspace layout (all 16B-aligned): ~44 MB total
    int*   cnt   = (int*)d_ws;            // SEGS
    int*   offs  = cnt + 1000000;         // SEGS+1 (padded to 1000004)
    int*   bsums = offs + 1000004;        // 1024
    int*   fill  = bsums + 1024;          // SEGS
    int*   esrc  = fill + 1000000;        // N_EDGES
    float* h0    = (float*)(esrc + 1600000);  // N*64
    float* h1    = h0 + 3200000;              // N*64

    // ---- CSR build (topology is layer-invariant; amortized over 4 layers) ----
    hipMemsetAsync(cnt, 0, (size_t)SEGS * sizeof(int), stream);
    hipMemsetAsync(fill, 0, (size_t)SEGS * sizeof(int), stream);
    count_kernel<<<2048, 256, 0, stream>>>(dst, et, cnt);
    scan1_kernel<<<SCAN_NB, 256, 0, stream>>>(cnt, offs, bsums, SEGS);
    scan_top_kernel<<<1, 1024, 0, stream>>>(bsums, SCAN_NB);
    scan_add_kernel<<<2048, 256, 0, stream>>>(offs, bsums, SEGS);
    set_total_kernel<<<1, 1, 0, stream>>>(offs);
    fill_kernel<<<2048, 256, 0, stream>>>(src, dst, et, offs, fill, esrc);

    const int GB = (N_NODES + 63) / 64;   // 782 blocks

    // ---- layer 0: IN=4 -> 64 ----
    rgcn_layer<4, false><<<GB, 256, 0, stream>>>(
        x, offs, esrc, W0, root0, b0, gamma, beta, rmean, rvar, h0);
    // ---- layer 1 ----
    rgcn_layer<64, false><<<GB, 256, 0, stream>>>(
        h0, offs, esrc, Wh, rooth, bh,
        gamma + 64, beta + 64, rmean + 64, rvar + 64, h1);
    // ---- layer 2 ----
    rgcn_layer<64, false><<<GB, 256, 0, stream>>>(
        h1, offs, esrc, Wh + (size_t)R_REL * 4096, rooth + 4096, bh + 64,
        gamma + 128, beta + 128, rmean + 128, rvar + 128, h0);
    // ---- layer 3 (+ReLU) -> out ----
    rgcn_layer<64, true><<<GB, 256, 0, stream>>>(
        h0, offs, esrc, Wh + (size_t)2 * R_REL * 4096, rooth + 2 * 4096, bh + 128,
        gamma + 192, beta + 192, rmean + 192, rvar + 192, out);
}

// Round 3
// 2494.558 us; speedup vs baseline: 1.1270x; 1.1270x over previous
//
#include <hip/hip_runtime.h>

#define N_NODES 50000
#define N_EDGES 1600000
#define R_REL   20
#define BN_EPS  1e-5f
#define SEGS    (N_NODES * R_REL)        /* 1,000,000 */
#define SCAN_NB ((SEGS + 1023) / 1024)   /* 977 */

// ---------------- CSR build: count per (rel, dst) segment ----------------
__global__ void count_kernel(const int* __restrict__ dst, const int* __restrict__ et,
                             int* __restrict__ cnt) {
    int stride = gridDim.x * blockDim.x;
    for (int e = blockIdx.x * blockDim.x + threadIdx.x; e < N_EDGES; e += stride)
        atomicAdd(&cnt[et[e] * N_NODES + dst[e]], 1);
}

// ---------------- 2-level exclusive scan over SEGS entries ----------------
__global__ __launch_bounds__(256) void scan1_kernel(const int* __restrict__ in,
                                                    int* __restrict__ out,
                                                    int* __restrict__ bsums, int n) {
    __shared__ int lds[256];
    int tid  = threadIdx.x;
    int base = blockIdx.x * 1024 + tid * 4;
    int v[4];
    #pragma unroll
    for (int j = 0; j < 4; ++j) v[j] = (base + j < n) ? in[base + j] : 0;
    int tsum = v[0] + v[1] + v[2] + v[3];
    lds[tid] = tsum;
    __syncthreads();
    for (int off = 1; off < 256; off <<= 1) {
        int t = (tid >= off) ? lds[tid - off] : 0;
        __syncthreads();
        lds[tid] += t;
        __syncthreads();
    }
    int run = lds[tid] - tsum;
    #pragma unroll
    for (int j = 0; j < 4; ++j) {
        if (base + j < n) out[base + j] = run;
        run += v[j];
    }
    if (tid == 255) bsums[blockIdx.x] = lds[255];
}

__global__ __launch_bounds__(1024) void scan_top_kernel(int* __restrict__ bsums, int nb) {
    __shared__ int lds[1024];
    int tid = threadIdx.x;
    int v = (tid < nb) ? bsums[tid] : 0;
    lds[tid] = v;
    __syncthreads();
    for (int off = 1; off < 1024; off <<= 1) {
        int t = (tid >= off) ? lds[tid - off] : 0;
        __syncthreads();
        lds[tid] += t;
        __syncthreads();
    }
    bsums[tid] = lds[tid] - v;
}

__global__ void scan_add_kernel(int* __restrict__ out, const int* __restrict__ bsums, int n) {
    int stride = gridDim.x * blockDim.x;
    for (int i = blockIdx.x * blockDim.x + threadIdx.x; i < n; i += stride)
        out[i] += bsums[i >> 10];
}

__global__ void set_total_kernel(int* __restrict__ offs) {
    offs[SEGS] = N_EDGES;
}

// ---------------- bucket-fill: epack = {src, dst, inv_cnt} sorted by (rel,dst) ----------
__global__ void fill_kernel(const int* __restrict__ src, const int* __restrict__ dst,
                            const int* __restrict__ et, const int* __restrict__ offs,
                            int* __restrict__ fill, int4* __restrict__ epack) {
    int stride = gridDim.x * blockDim.x;
    for (int e = blockIdx.x * blockDim.x + threadIdx.x; e < N_EDGES; e += stride) {
        int seg = et[e] * N_NODES + dst[e];
        int pos = offs[seg] + atomicAdd(&fill[seg], 1);
        float ic = 1.0f / fmaxf((float)(offs[seg + 1] - offs[seg]), 1.0f);
        epack[pos] = make_int4(src[e], dst[e], __float_as_int(ic), 0);
    }
}

// ---------------- fused layer: edge-parallel gather-mean + per-rel GEMM + BN (+ReLU) ----
// 32-node tile, 256 threads (4 waves). Per relation r: zero A + stage W -> barrier ->
// edge-parallel gather (contiguous epack range, LDS float atomics, lane=feature) ->
// barrier -> GEMM accumulate. r==R_REL is the root term. Epilogue: bias+BN(+ReLU).
template <int F, bool RELU>
__global__ __launch_bounds__(256) void rgcn_layer(
    const float* __restrict__ hin, const int* __restrict__ offs,
    const int4* __restrict__ epack,
    const float* __restrict__ W, const float* __restrict__ root,
    const float* __restrict__ bias, const float* __restrict__ gamma,
    const float* __restrict__ beta, const float* __restrict__ rmean,
    const float* __restrict__ rvar, float* __restrict__ out) {
    constexpr int TN = 32;
    constexpr int AP = (F == 64) ? 68 : 12;   // padded row stride (floats), 16B-aligned
    constexpr int FV = F / 4;

    __shared__ float Alds[TN * AP];
    __shared__ float Wlds[F * 64];

    const int tid  = threadIdx.x;
    const int lane = tid & 63;
    const int wv   = tid >> 6;
    const int og   = tid & 15;
    const int nl   = tid >> 4;
    const int o    = og * 4;
    const int n0   = blockIdx.x * TN;
    const int nend = min(n0 + TN, N_NODES);

    float acc0[4] = {0.f, 0.f, 0.f, 0.f};
    float acc1[4] = {0.f, 0.f, 0.f, 0.f};

    for (int r = 0; r <= R_REL; ++r) {
        __syncthreads();   // previous GEMM done reading Alds/Wlds
        if (r < R_REL) {
            // zero A tile + stage W[r]
            float4 z4 = make_float4(0.f, 0.f, 0.f, 0.f);
            for (int i = tid; i < TN * AP / 4; i += 256) ((float4*)Alds)[i] = z4;
            const float* Wb = W + (size_t)r * F * 64;
            for (int i = tid; i < F * 16; i += 256)
                ((float4*)Wlds)[i] = ((const float4*)Wb)[i];
            __syncthreads();   // zeros visible before atomics
            int e0 = offs[r * N_NODES + n0];
            int e1 = offs[r * N_NODES + nend];
            if (F == 64) {
                // one edge per wave-iteration: lane = feature
                #pragma unroll 2
                for (int e = e0 + wv; e < e1; e += 4) {
                    int4 p = epack[e];
                    float v = hin[(size_t)p.x * 64 + lane] * __int_as_float(p.z);
                    atomicAdd(&Alds[(p.y - n0) * AP + lane], v);
                }
            } else {
                // 16 edges per wave-iteration: lane>>2 = edge slot, lane&3 = feature
                for (int base = e0 + wv * 16; base < e1; base += 64) {
                    int e = base + (lane >> 2);
                    if (e < e1) {
                        int4 p = epack[e];
                        float v = hin[(size_t)p.x * 4 + (lane & 3)] * __int_as_float(p.z);
                        atomicAdd(&Alds[(p.y - n0) * AP + (lane & 3)], v);
                    }
                }
            }
        } else {
            // root term: A = hin tile rows, W = root
            for (int i = tid; i < TN * FV; i += 256) {
                int n = i / FV, c = i % FV;
                int gn = n0 + n;
                float4 val = make_float4(0.f, 0.f, 0.f, 0.f);
                if (gn < N_NODES)
                    val = *(const float4*)&hin[(size_t)gn * F + c * 4];
                *(float4*)&Alds[n * AP + c * 4] = val;
            }
            for (int i = tid; i < F * 16; i += 256)
                ((float4*)Wlds)[i] = ((const float4*)root)[i];
        }
        __syncthreads();

        // GEMM: 2 nodes x 4 outputs per thread
        #pragma unroll
        for (int c = 0; c < FV; ++c) {
            float a0[4], a1[4];
            *(float4*)a0 = *(const float4*)&Alds[nl * AP + c * 4];
            *(float4*)a1 = *(const float4*)&Alds[(nl + 16) * AP + c * 4];
            #pragma unroll
            for (int j = 0; j < 4; ++j) {
                float w[4];
                *(float4*)w = *(const float4*)&Wlds[(c * 4 + j) * 64 + o];
                #pragma unroll
                for (int q = 0; q < 4; ++q) {
                    acc0[q] += a0[j] * w[q];
                    acc1[q] += a1[j] * w[q];
                }
            }
        }
    }

    // epilogue: bias + BN (+ReLU)
    float bia[4], rm[4], rv[4], g[4], bt[4], sc[4];
    *(float4*)bia = *(const float4*)&bias[o];
    *(float4*)rm  = *(const float4*)&rmean[o];
    *(float4*)rv  = *(const float4*)&rvar[o];
    *(float4*)g   = *(const float4*)&gamma[o];
    *(float4*)bt  = *(const float4*)&beta[o];
    #pragma unroll
    for (int q = 0; q < 4; ++q) sc[q] = g[q] * rsqrtf(rv[q] + BN_EPS);

    int gn0 = n0 + nl, gn1 = n0 + nl + 16;
    if (gn0 < N_NODES) {
        float ov[4];
        #pragma unroll
        for (int q = 0; q < 4; ++q) {
            float v = acc0[q] + bia[q];
            v = (v - rm[q]) * sc[q] + bt[q];
            if (RELU) v = fmaxf(v, 0.f);
            ov[q] = v;
        }
        *(float4*)&out[(size_t)gn0 * 64 + o] = *(const float4*)ov;
    }
    if (gn1 < N_NODES) {
        float ov[4];
        #pragma unroll
        for (int q = 0; q < 4; ++q) {
            float v = acc1[q] + bia[q];
            v = (v - rm[q]) * sc[q] + bt[q];
            if (RELU) v = fmaxf(v, 0.f);
            ov[q] = v;
        }
        *(float4*)&out[(size_t)gn1 * 64 + o] = *(const float4*)ov;
    }
}

extern "C" void kernel_launch(void* const* d_in, const int* in_sizes, int n_in,
                              void* d_out, int out_size, void* d_ws, size_t ws_size,
                              hipStream_t stream) {
    const float* x     = (const float*)d_in[0];
    const int*   ei    = (const int*)d_in[1];
    const int*   et    = (const int*)d_in[2];
    const float* W0    = (const float*)d_in[3];
    const float* root0 = (const float*)d_in[4];
    const float* b0    = (const float*)d_in[5];
    const float* Wh    = (const float*)d_in[6];
    const float* rooth = (const float*)d_in[7];
    const float* bh    = (const float*)d_in[8];
    const float* gamma = (const float*)d_in[9];
    const float* beta  = (const float*)d_in[10];
    const float* rmean = (const float*)d_in[11];
    const float* rvar  = (const float*)d_in[12];
    float* out = (float*)d_out;

    const int* src = ei;
    const int* dst = ei + N_EDGES;

    // workspace layout (~59.2 MB total)
    int*  fill  = (int*)d_ws;                 // SEGS
    int*  offs  = fill + 1000000;             // SEGS+1 (padded to 1000004)
    int*  bsums = offs + 1000004;             // 1024
    int4* epack = (int4*)(bsums + 1024);      // N_EDGES (16B-aligned: byte off 8,004,112)
    float* h0   = (float*)(epack + 1600000);  // N*64
    float* h1   = h0 + 3200000;               // N*64

    // ---- CSR build, (rel, dst)-ordered ----
    hipMemsetAsync(fill, 0, (size_t)SEGS * sizeof(int), stream);
    count_kernel<<<2048, 256, 0, stream>>>(dst, et, fill);
    scan1_kernel<<<SCAN_NB, 256, 0, stream>>>(fill, offs, bsums, SEGS);
    scan_top_kernel<<<1, 1024, 0, stream>>>(bsums, SCAN_NB);
    scan_add_kernel<<<2048, 256, 0, stream>>>(offs, bsums, SEGS);
    set_total_kernel<<<1, 1, 0, stream>>>(offs);
    hipMemsetAsync(fill, 0, (size_t)SEGS * sizeof(int), stream);
    fill_kernel<<<2048, 256, 0, stream>>>(src, dst, et, offs, fill, epack);

    const int GB = (N_NODES + 31) / 32;   // 1563 blocks

    // ---- layer 0: IN=4 -> 64 ----
    rgcn_layer<4, false><<<GB, 256, 0, stream>>>(
        x, offs, epack, W0, root0, b0, gamma, beta, rmean, rvar, h0);
    // ---- layer 1 ----
    rgcn_layer<64, false><<<GB, 256, 0, stream>>>(
        h0, offs, epack, Wh, rooth, bh,
        gamma + 64, beta + 64, rmean + 64, rvar + 64, h1);
    // ---- layer 2 ----
    rgcn_layer<64, false><<<GB, 256, 0, stream>>>(
        h1, offs, epack, Wh + (size_t)R_REL * 4096, rooth + 4096, bh + 64,
        gamma + 128, beta + 128, rmean + 128, rvar + 128, h0);
    // ---- layer 3 (+ReLU) -> out ----
    rgcn_layer<64, true><<<GB, 256, 0, stream>>>(
        h0, offs, epack, Wh + (size_t)2 * R_REL * 4096, rooth + 2 * 4096, bh + 128,
        gamma + 192, beta + 192, rmean + 192, rvar + 192, out);
}

// Round 4
// 2236.383 us; speedup vs baseline: 1.2571x; 1.1154x over previous
//
#include <hip/hip_runtime.h>

#define NN 50000
#define NE 1600000
#define RR 20
#define BN_EPS 1e-5f
#define SEGS (NN * RR)                    /* 1,000,000 */
#define SCAN_NB ((SEGS + 1023) / 1024)    /* 977 */

typedef __attribute__((ext_vector_type(8))) short bf16x8;
typedef __attribute__((ext_vector_type(4))) float f32x4;

__device__ __forceinline__ unsigned short f2bf(float f) {
    unsigned u = __float_as_uint(f);
    u += 0x7fff + ((u >> 16) & 1);        // RNE
    return (unsigned short)(u >> 16);
}
__device__ __forceinline__ float bfl(unsigned u) { return __uint_as_float(u << 16); }
__device__ __forceinline__ float bfh(unsigned u) { return __uint_as_float(u & 0xffff0000u); }

// ---------------- CSR build: count per (rel, dst) segment ----------------
__global__ void count_kernel(const int* __restrict__ dst, const int* __restrict__ et,
                             int* __restrict__ cnt) {
    int stride = gridDim.x * blockDim.x;
    for (int e = blockIdx.x * blockDim.x + threadIdx.x; e < NE; e += stride)
        atomicAdd(&cnt[et[e] * NN + dst[e]], 1);
}

__global__ __launch_bounds__(256) void scan1_kernel(const int* __restrict__ in,
                                                    int* __restrict__ out,
                                                    int* __restrict__ bsums, int n) {
    __shared__ int lds[256];
    int tid  = threadIdx.x;
    int base = blockIdx.x * 1024 + tid * 4;
    int v[4];
    #pragma unroll
    for (int j = 0; j < 4; ++j) v[j] = (base + j < n) ? in[base + j] : 0;
    int tsum = v[0] + v[1] + v[2] + v[3];
    lds[tid] = tsum;
    __syncthreads();
    for (int off = 1; off < 256; off <<= 1) {
        int t = (tid >= off) ? lds[tid - off] : 0;
        __syncthreads();
        lds[tid] += t;
        __syncthreads();
    }
    int run = lds[tid] - tsum;
    #pragma unroll
    for (int j = 0; j < 4; ++j) {
        if (base + j < n) out[base + j] = run;
        run += v[j];
    }
    if (tid == 255) bsums[blockIdx.x] = lds[255];
}

__global__ __launch_bounds__(1024) void scan_top_kernel(int* __restrict__ bsums, int nb) {
    __shared__ int lds[1024];
    int tid = threadIdx.x;
    int v = (tid < nb) ? bsums[tid] : 0;
    lds[tid] = v;
    __syncthreads();
    for (int off = 1; off < 1024; off <<= 1) {
        int t = (tid >= off) ? lds[tid - off] : 0;
        __syncthreads();
        lds[tid] += t;
        __syncthreads();
    }
    bsums[tid] = lds[tid] - v;
}

__global__ void scan_add_kernel(int* __restrict__ out, const int* __restrict__ bsums, int n) {
    int stride = gridDim.x * blockDim.x;
    for (int i = blockIdx.x * blockDim.x + threadIdx.x; i < n; i += stride)
        out[i] += bsums[i >> 10];
}

__global__ void set_total_kernel(int* __restrict__ offs) { offs[SEGS] = NE; }

// ---------------- bucket-fill: epack = src | (dst&31)<<20, sorted by (rel,dst) --------
__global__ void fill_kernel(const int* __restrict__ src, const int* __restrict__ dst,
                            const int* __restrict__ et, const int* __restrict__ offs,
                            int* __restrict__ fill, unsigned* __restrict__ epack) {
    int stride = gridDim.x * blockDim.x;
    for (int e = blockIdx.x * blockDim.x + threadIdx.x; e < NE; e += stride) {
        int seg = et[e] * NN + dst[e];
        int pos = offs[seg] + atomicAdd(&fill[seg], 1);
        epack[pos] = (unsigned)src[e] | ((unsigned)(dst[e] & 31) << 20);
    }
}

// ---------------- weight prep: Wt[l][r][n][k] bf16 (transposed), r=20 is root ---------
__global__ __launch_bounds__(256) void wprep_kernel(const float* __restrict__ Wh,
                                                    const float* __restrict__ rooth,
                                                    unsigned short* __restrict__ Wt) {
    int l = blockIdx.x / 21, r = blockIdx.x % 21;
    const float* Ws = (r < 20) ? Wh + ((size_t)l * 20 + r) * 4096
                               : rooth + (size_t)l * 4096;
    unsigned short* Wd = Wt + ((size_t)l * 21 + r) * 4096;
    int t = threadIdx.x;
    int n4 = (t & 15) * 4;
    for (int k = t >> 4; k < 64; k += 16) {
        float4 w = *(const float4*)&Ws[(size_t)k * 64 + n4];
        Wd[(n4 + 0) * 64 + k] = f2bf(w.x);
        Wd[(n4 + 1) * 64 + k] = f2bf(w.y);
        Wd[(n4 + 2) * 64 + k] = f2bf(w.z);
        Wd[(n4 + 3) * 64 + k] = f2bf(w.w);
    }
}

// ---------------- layer 0: fp32 VALU GEMM (K=84 tiny), out bf16 ----------------
__global__ __launch_bounds__(256) void rgcn_l0(
    const float* __restrict__ x, const int* __restrict__ offs,
    const unsigned* __restrict__ epack,
    const float* __restrict__ W0, const float* __restrict__ root0,
    const float* __restrict__ b0, const float* __restrict__ gamma,
    const float* __restrict__ beta, const float* __restrict__ rmean,
    const float* __restrict__ rvar, unsigned short* __restrict__ outb) {
    constexpr int AP = 12;
    __shared__ float Alds[32 * AP];
    __shared__ float Wlds[4 * 64];
    const int tid = threadIdx.x;
    const int lane = tid & 63;
    const int wv = tid >> 6;
    const int og = tid & 15, nl = tid >> 4, o = og * 4;
    const int n0 = blockIdx.x * 32;
    const int nend = min(n0 + 32, NN);
    float acc0[4] = {0.f, 0.f, 0.f, 0.f}, acc1[4] = {0.f, 0.f, 0.f, 0.f};

    for (int r = 0; r <= RR; ++r) {
        __syncthreads();
        if (r < RR) {
            for (int i = tid; i < 32 * AP / 4; i += 256)
                ((float4*)Alds)[i] = make_float4(0.f, 0.f, 0.f, 0.f);
            const float* Wb = W0 + (size_t)r * 256;
            for (int i = tid; i < 64; i += 256)
                ((float4*)Wlds)[i] = ((const float4*)Wb)[i];
            __syncthreads();
            int e0 = offs[r * NN + n0], e1 = offs[r * NN + nend];
            int sl = lane >> 2, f = lane & 3;
            for (int eb = e0 + wv * 16; eb < e1; eb += 64) {
                int e = eb + sl;
                if (e < e1) {
                    unsigned p = epack[e];
                    int srcn = p & 0xFFFFF, dl = p >> 20;
                    atomicAdd(&Alds[dl * AP + f], x[(size_t)srcn * 4 + f]);
                }
            }
            __syncthreads();
            if (tid < 128) {
                int m = tid >> 2, f2 = tid & 3;
                int gs = min(n0 + m, NN - 1);
                int seg = r * NN + gs;
                int cnt = offs[seg + 1] - offs[seg];
                Alds[m * AP + f2] *= 1.0f / (float)(cnt > 0 ? cnt : 1);
            }
        } else {
            for (int i = tid; i < 128; i += 256) {
                int m = i >> 2, f2 = i & 3;
                int gn = n0 + m;
                Alds[m * AP + f2] = (gn < NN) ? x[(size_t)gn * 4 + f2] : 0.f;
            }
            for (int i = tid; i < 64; i += 256)
                ((float4*)Wlds)[i] = ((const float4*)root0)[i];
        }
        __syncthreads();
        float a0[4], a1[4];
        *(float4*)a0 = *(const float4*)&Alds[nl * AP];
        *(float4*)a1 = *(const float4*)&Alds[(nl + 16) * AP];
        #pragma unroll
        for (int j = 0; j < 4; ++j) {
            float w[4];
            *(float4*)w = *(const float4*)&Wlds[j * 64 + o];
            #pragma unroll
            for (int q = 0; q < 4; ++q) {
                acc0[q] += a0[j] * w[q];
                acc1[q] += a1[j] * w[q];
            }
        }
    }

    float bia[4], rm[4], rv[4], g[4], bt[4], sc[4];
    *(float4*)bia = *(const float4*)&b0[o];
    *(float4*)rm  = *(const float4*)&rmean[o];
    *(float4*)rv  = *(const float4*)&rvar[o];
    *(float4*)g   = *(const float4*)&gamma[o];
    *(float4*)bt  = *(const float4*)&beta[o];
    #pragma unroll
    for (int q = 0; q < 4; ++q) sc[q] = g[q] * rsqrtf(rv[q] + BN_EPS);

    int gn0 = n0 + nl, gn1 = n0 + nl + 16;
    if (gn0 < NN) {
        ushort4 pk;
        pk.x = f2bf((acc0[0] + bia[0] - rm[0]) * sc[0] + bt[0]);
        pk.y = f2bf((acc0[1] + bia[1] - rm[1]) * sc[1] + bt[1]);
        pk.z = f2bf((acc0[2] + bia[2] - rm[2]) * sc[2] + bt[2]);
        pk.w = f2bf((acc0[3] + bia[3] - rm[3]) * sc[3] + bt[3]);
        *(ushort4*)&outb[(size_t)gn0 * 64 + o] = pk;
    }
    if (gn1 < NN) {
        ushort4 pk;
        pk.x = f2bf((acc1[0] + bia[0] - rm[0]) * sc[0] + bt[0]);
        pk.y = f2bf((acc1[1] + bia[1] - rm[1]) * sc[1] + bt[1]);
        pk.z = f2bf((acc1[2] + bia[2] - rm[2]) * sc[2] + bt[2]);
        pk.w = f2bf((acc1[3] + bia[3] - rm[3]) * sc[3] + bt[3]);
        *(ushort4*)&outb[(size_t)gn1 * 64 + o] = pk;
    }
}

// ---------------- hidden layer: bf16 gather + MFMA GEMM + BN (+ReLU to fp32) ---------
// 32-node tile, 256 thr (4 waves). Per rel: gather(sum raw rows, LDS fp32 atomics) |bar|
// cvt(scale by 1/cnt, ->bf16 swizzled, rezero Aacc) + stageW |bar| mfma accumulate.
// r=20 is root (A = hin rows). Wave wv: rows m0=(wv&1)*16, cols nc0=(wv>>1)*32.
template <bool LAST>
__global__ __launch_bounds__(256) void rgcn_hidden(
    const unsigned short* __restrict__ hin, const int* __restrict__ offs,
    const unsigned* __restrict__ epack, const unsigned short* __restrict__ WtL,
    const float* __restrict__ bias, const float* __restrict__ gamma,
    const float* __restrict__ beta, const float* __restrict__ rmean,
    const float* __restrict__ rvar, unsigned short* __restrict__ outb,
    float* __restrict__ outf) {
    constexpr int AS = 68;                    // Aacc stride (fp32): 272B rows, 16B-aligned
    __shared__ float Aacc[32 * AS];           // 8704 B
    __shared__ unsigned short Abf[32 * 64];   // 4096 B, swizzled
    __shared__ unsigned short Wlds[64 * 64];  // 8192 B, swizzled [n][k]

    const int tid  = threadIdx.x;
    const int lane = tid & 63;
    const int wv   = tid >> 6;
    const int n0   = blockIdx.x * 32;
    const int nend = min(n0 + 32, NN);

    const int m0   = (wv & 1) * 16;
    const int nc0  = (wv >> 1) * 32;
    const int frow = lane & 15;
    const int kgrp = lane >> 4;
    f32x4 acc0 = {0.f, 0.f, 0.f, 0.f}, acc1 = {0.f, 0.f, 0.f, 0.f};

    for (int i = tid; i < 32 * AS / 4; i += 256)
        ((float4*)Aacc)[i] = make_float4(0.f, 0.f, 0.f, 0.f);
    __syncthreads();

    const int sl = lane >> 3;   // edge slot 0..7
    const int fl = lane & 7;    // 16B feature chunk
    const int cm = tid >> 3;    // cvt row 0..31
    const int cc = tid & 7;     // cvt 16B chunk

    for (int r = 0; r <= RR; ++r) {
        if (r < RR) {
            int e0 = offs[r * NN + n0];
            int e1 = offs[r * NN + nend];
            #pragma unroll 2
            for (int eb = e0 + wv * 8; eb < e1; eb += 32) {
                int e = eb + sl;
                if (e < e1) {
                    unsigned p = epack[e];
                    int srcn = p & 0xFFFFF;
                    int dl = p >> 20;
                    uint4 row = *(const uint4*)&hin[(size_t)srcn * 64 + fl * 8];
                    float* ap = &Aacc[dl * AS + fl * 8];
                    atomicAdd(ap + 0, bfl(row.x));
                    atomicAdd(ap + 1, bfh(row.x));
                    atomicAdd(ap + 2, bfl(row.y));
                    atomicAdd(ap + 3, bfh(row.y));
                    atomicAdd(ap + 4, bfl(row.z));
                    atomicAdd(ap + 5, bfh(row.z));
                    atomicAdd(ap + 6, bfl(row.w));
                    atomicAdd(ap + 7, bfh(row.w));
                }
            }
        }
        __syncthreads();   // gather done; mfma(r-1) done reading Abf/Wlds

        // cvt + rezero + stageW
        {
            uint4 pk;
            if (r < RR) {
                int gs = min(n0 + cm, NN - 1);
                int seg = r * NN + gs;
                int cnt = offs[seg + 1] - offs[seg];
                float ic = 1.0f / (float)(cnt > 0 ? cnt : 1);
                float4 v0 = *(float4*)&Aacc[cm * AS + cc * 8];
                float4 v1 = *(float4*)&Aacc[cm * AS + cc * 8 + 4];
                *(float4*)&Aacc[cm * AS + cc * 8]     = make_float4(0.f, 0.f, 0.f, 0.f);
                *(float4*)&Aacc[cm * AS + cc * 8 + 4] = make_float4(0.f, 0.f, 0.f, 0.f);
                pk.x = (unsigned)f2bf(v0.x * ic) | ((unsigned)f2bf(v0.y * ic) << 16);
                pk.y = (unsigned)f2bf(v0.z * ic) | ((unsigned)f2bf(v0.w * ic) << 16);
                pk.z = (unsigned)f2bf(v1.x * ic) | ((unsigned)f2bf(v1.y * ic) << 16);
                pk.w = (unsigned)f2bf(v1.z * ic) | ((unsigned)f2bf(v1.w * ic) << 16);
            } else {
                int gn = n0 + cm;
                pk = (gn < NN) ? *(const uint4*)&hin[(size_t)gn * 64 + cc * 8]
                               : make_uint4(0u, 0u, 0u, 0u);
            }
            int ab = (cm * 128 + cc * 16) ^ ((cm & 7) << 4);
            *(uint4*)((char*)Abf + ab) = pk;

            const uint4* Ws = (const uint4*)(WtL + (size_t)r * 4096);
            #pragma unroll
            for (int it = 0; it < 2; ++it) {
                int idx = tid * 2 + it;           // 512 chunks of 16B
                int n = idx >> 3, c2 = idx & 7;
                int wb = (n * 128 + c2 * 16) ^ ((n & 7) << 4);
                *(uint4*)((char*)Wlds + wb) = Ws[idx];
            }
        }
        __syncthreads();   // Abf/Wlds ready

        // mfma accumulate
        {
            int ar = m0 + frow;
            #pragma unroll
            for (int ks = 0; ks < 2; ++ks) {
                int abyte = (ar * 128 + ks * 64 + kgrp * 16) ^ ((ar & 7) << 4);
                bf16x8 a = *(bf16x8*)((char*)Abf + abyte);
                int br0 = nc0 + frow;
                int b0b = (br0 * 128 + ks * 64 + kgrp * 16) ^ ((br0 & 7) << 4);
                bf16x8 b0 = *(bf16x8*)((char*)Wlds + b0b);
                int br1 = nc0 + 16 + frow;
                int b1b = (br1 * 128 + ks * 64 + kgrp * 16) ^ ((br1 & 7) << 4);
                bf16x8 b1 = *(bf16x8*)((char*)Wlds + b1b);
                acc0 = __builtin_amdgcn_mfma_f32_16x16x32_bf16(a, b0, acc0, 0, 0, 0);
                acc1 = __builtin_amdgcn_mfma_f32_16x16x32_bf16(a, b1, acc1, 0, 0, 0);
            }
        }
    }

    // epilogue: bias + BN (+ReLU); D layout: col=lane&15, row=(lane>>4)*4+reg
    #pragma unroll
    for (int fj = 0; fj < 2; ++fj) {
        f32x4 acc = fj ? acc1 : acc0;
        int col = nc0 + fj * 16 + frow;
        float bi = bias[col], g = gamma[col], bt = beta[col];
        float rm = rmean[col], rv = rvar[col];
        float sc = g * rsqrtf(rv + BN_EPS);
        #pragma unroll
        for (int reg = 0; reg < 4; ++reg) {
            int node = n0 + m0 + kgrp * 4 + reg;
            if (node < NN) {
                float v = (acc[reg] + bi - rm) * sc + bt;
                if (LAST) {
                    outf[(size_t)node * 64 + col] = fmaxf(v, 0.f);
                } else {
                    outb[(size_t)node * 64 + col] = f2bf(v);
                }
            }
        }
    }
}

extern "C" void kernel_launch(void* const* d_in, const int* in_sizes, int n_in,
                              void* d_out, int out_size, void* d_ws, size_t ws_size,
                              hipStream_t stream) {
    const float* x     = (const float*)d_in[0];
    const int*   ei    = (const int*)d_in[1];
    const int*   et    = (const int*)d_in[2];
    const float* W0    = (const float*)d_in[3];
    const float* root0 = (const float*)d_in[4];
    const float* b0    = (const float*)d_in[5];
    const float* Wh    = (const float*)d_in[6];
    const float* rooth = (const float*)d_in[7];
    const float* bh    = (const float*)d_in[8];
    const float* gamma = (const float*)d_in[9];
    const float* beta  = (const float*)d_in[10];
    const float* rmean = (const float*)d_in[11];
    const float* rvar  = (const float*)d_in[12];
    float* out = (float*)d_out;

    const int* src = ei;
    const int* dst = ei + NE;

    // workspace (~27.7 MB)
    int*      fill  = (int*)d_ws;                       // 1,000,000
    int*      offs  = fill + 1000000;                   // 1,000,004
    int*      bsums = offs + 1000004;                   // 1,024
    unsigned* epack = (unsigned*)(bsums + 1024);        // 1,600,000 u32
    unsigned short* Wt = (unsigned short*)(epack + 1600000);  // 3*21*4096
    unsigned short* h0 = Wt + 3 * 21 * 4096;            // N*64 bf16
    unsigned short* h1 = h0 + NN * 64;                  // N*64 bf16

    // ---- CSR build, (rel, dst)-ordered ----
    hipMemsetAsync(fill, 0, (size_t)SEGS * sizeof(int), stream);
    count_kernel<<<2048, 256, 0, stream>>>(dst, et, fill);
    scan1_kernel<<<SCAN_NB, 256, 0, stream>>>(fill, offs, bsums, SEGS);
    scan_top_kernel<<<1, 1024, 0, stream>>>(bsums, SCAN_NB);
    scan_add_kernel<<<2048, 256, 0, stream>>>(offs, bsums, SEGS);
    set_total_kernel<<<1, 1, 0, stream>>>(offs);
    hipMemsetAsync(fill, 0, (size_t)SEGS * sizeof(int), stream);
    fill_kernel<<<2048, 256, 0, stream>>>(src, dst, et, offs, fill, epack);
    wprep_kernel<<<63, 256, 0, stream>>>(Wh, rooth, Wt);

    const int GB = (NN + 31) / 32;   // 1563 blocks

    rgcn_l0<<<GB, 256, 0, stream>>>(
        x, offs, epack, W0, root0, b0, gamma, beta, rmean, rvar, h0);
    rgcn_hidden<false><<<GB, 256, 0, stream>>>(
        h0, offs, epack, Wt, bh, gamma + 64, beta + 64, rmean + 64, rvar + 64,
        h1, nullptr);
    rgcn_hidden<false><<<GB, 256, 0, stream>>>(
        h1, offs, epack, Wt + 21 * 4096, bh + 64, gamma + 128, beta + 128,
        rmean + 128, rvar + 128, h0, nullptr);
    rgcn_hidden<true><<<GB, 256, 0, stream>>>(
        h0, offs, epack, Wt + 42 * 4096, bh + 128, gamma + 192, beta + 192,
        rmean + 192, rvar + 192, nullptr, out);
}